// Round 1
// baseline (1997.942 us; speedup 1.0000x reference)
//
#include <hip/hip_runtime.h>

#define ANG 9
#define BATCH 4
#define CIN 64
#define COUT 64
#define HW 48
#define IN_HW 432
#define KK 81            // 9x9 taps
#define SPOS 2304        // 48*48
#define DDIM 68          // 17 disparities * 4 replicas

// ---------------------------------------------------------------------------
// conv_kernel: one integer disparity d per block-group; computes
// conv[d][b][co][oy][ox] and stashes it in d_out at D-slot 8*di (an even-t
// slice, which will be zeroed later). Block = 256 threads covers
// 64 co x (2 oy x 16 ox). Per-ci LDS staging of weights + x patch.
// ---------------------------------------------------------------------------
__global__ __launch_bounds__(256, 4) void conv_kernel(
    const float* __restrict__ x,
    const float* __restrict__ w,
    float* __restrict__ out) {
  __shared__ float lw[COUT * KK];  // [co][k]  (natural weight layout)
  __shared__ float lx[KK * 32];    // [k][r(2)][c(16)]

  int bi  = blockIdx.x;
  int oxt = bi % 3;            // ox tile: 3 x 16
  int oy2 = (bi / 3) % 24;     // oy pair: 24 x 2
  int b   = (bi / 72) % BATCH;
  int di  = bi / 288;          // 0..8  -> d = di-4
  int d   = di - 4;

  int dil, pad;
  if (d < 0)      { dil = (-d) * ANG + 1; pad = (-d) * 36; }
  else if (d == 0){ dil = 1;              pad = 0; }
  else            { dil = d * ANG - 1;    pad = d * 36 - 8; }

  int t  = threadIdx.x;
  int tx = t & 15;   // ox lane
  int ty = t >> 4;   // co group (4 co's each)

  float acc[4][2] = {};
  const float* xb = x + (size_t)b * CIN * IN_HW * IN_HW;

  for (int ci = 0; ci < CIN; ++ci) {
    __syncthreads();
    // stage w[:, ci, :, :] -> lw[co*81 + k]; coalesced (81 contiguous per co)
    for (int s = t; s < COUT * KK; s += 256) {
      int co = s / KK;
      int k  = s - co * KK;
      lw[s] = w[((size_t)co * CIN + ci) * KK + k];
    }
    // stage x patch: for each tap k=(ky,kx), the 2x16 output positions
    const float* xc = xb + (size_t)ci * IN_HW * IN_HW;
    for (int s = t; s < KK * 32; s += 256) {
      int k   = s >> 5;
      int rem = s & 31;
      int r = rem >> 4, c = rem & 15;
      int ky = k / ANG, kx = k - ky * ANG;
      int oy = oy2 * 2 + r, ox = oxt * 16 + c;
      int iy = oy * ANG - pad + ky * dil;
      int ix = ox * ANG - pad + kx * dil;
      float v = 0.f;
      if ((unsigned)iy < IN_HW && (unsigned)ix < IN_HW)
        v = xc[iy * IN_HW + ix];
      lx[s] = v;
    }
    __syncthreads();

    const float* lwp = lw + ty * 4 * KK;
#pragma unroll 9
    for (int k = 0; k < KK; ++k) {
      float x0 = lx[k * 32 + tx];
      float x1 = lx[k * 32 + 16 + tx];
      float w0 = lwp[k];
      float w1 = lwp[k + KK];
      float w2 = lwp[k + 2 * KK];
      float w3 = lwp[k + 3 * KK];
      acc[0][0] += w0 * x0; acc[0][1] += w0 * x1;
      acc[1][0] += w1 * x0; acc[1][1] += w1 * x1;
      acc[2][0] += w2 * x0; acc[2][1] += w2 * x1;
      acc[3][0] += w3 * x0; acc[3][1] += w3 * x1;
    }
  }

  // stash conv result at D-slot 8*di (even-t slice, replica 0)
  int oy = oy2 * 2, ox = oxt * 16 + tx;
#pragma unroll
  for (int j = 0; j < 4; ++j) {
    int co = ty * 4 + j;
    size_t base = (((size_t)(b * COUT + co) * DDIM) + 8 * di) * SPOS;
    out[base + (size_t)oy * HW + ox]       = acc[j][0];
    out[base + (size_t)(oy + 1) * HW + ox] = acc[j][1];
  }
}

// ---------------------------------------------------------------------------
// blend_kernel: odd-t slices = 0.5*(conv[d] + conv[d+1]), 4 replicas each.
// Reads the temps stashed at D = 8*j (disjoint from the D's it writes).
// ---------------------------------------------------------------------------
__global__ __launch_bounds__(256) void blend_kernel(float* __restrict__ out) {
  int p  = blockIdx.x * 256 + threadIdx.x;   // p < 4*64*2304
  int bc = p / SPOS;
  int s  = p - bc * SPOS;
  size_t base = (size_t)bc * DDIM * SPOS + s;
  float tv[9];
#pragma unroll
  for (int j = 0; j < 9; ++j) tv[j] = out[base + (size_t)(8 * j) * SPOS];
#pragma unroll
  for (int j = 0; j < 8; ++j) {
    float v = 0.5f * (tv[j] + tv[j + 1]);
    size_t o = base + (size_t)(8 * j + 4) * SPOS;
    out[o]            = v;
    out[o + SPOS]     = v;
    out[o + 2 * SPOS] = v;
    out[o + 3 * SPOS] = v;
  }
}

// ---------------------------------------------------------------------------
// zero_kernel: even-t slices (including the temp slots) are exactly zero.
// ---------------------------------------------------------------------------
__global__ __launch_bounds__(256) void zero_kernel(float* __restrict__ out) {
  int p  = blockIdx.x * 256 + threadIdx.x;
  int bc = p / SPOS;
  int s  = p - bc * SPOS;
  size_t base = (size_t)bc * DDIM * SPOS + s;
#pragma unroll
  for (int j = 0; j < 9; ++j) {
    size_t o = base + (size_t)(8 * j) * SPOS;
    out[o]            = 0.f;
    out[o + SPOS]     = 0.f;
    out[o + 2 * SPOS] = 0.f;
    out[o + 3 * SPOS] = 0.f;
  }
}

extern "C" void kernel_launch(void* const* d_in, const int* in_sizes, int n_in,
                              void* d_out, int out_size, void* d_ws, size_t ws_size,
                              hipStream_t stream) {
  const float* x = (const float*)d_in[0];   // [4, 64, 432, 432]
  const float* w = (const float*)d_in[1];   // [64, 64, 9, 9]
  float* out = (float*)d_out;               // [4, 64, 68, 48, 48]

  // 1) 9 convs -> stash into even-t D-slots of out
  conv_kernel<<<dim3(9 * 4 * 24 * 3), dim3(256), 0, stream>>>(x, w, out);
  // 2) odd-t slices = 0.5*(conv[d]+conv[d+1]) x 4 replicas
  blend_kernel<<<dim3((BATCH * COUT * SPOS) / 256), dim3(256), 0, stream>>>(out);
  // 3) even-t slices = 0
  zero_kernel<<<dim3((BATCH * COUT * SPOS) / 256), dim3(256), 0, stream>>>(out);
}

// Round 2
// 605.582 us; speedup vs baseline: 3.2992x; 3.2992x over previous
//
#include <hip/hip_runtime.h>

#define ANG 9
#define BATCH 4
#define CIN 64
#define COUT 64
#define HW 48
#define IN_HW 432
#define KK 81            // 9x9 taps
#define SPOS 2304        // 48*48
#define DDIM 68          // 17 disparities * 4 replicas

typedef __attribute__((ext_vector_type(8))) short short8;
typedef __attribute__((ext_vector_type(4))) float f32x4;

#define BSLAB (KK * SPOS * CIN)           // elems per batch in xvu = 11,943,936
#define XVU_ELEMS (4 * BSLAB)
#define XVU_BYTES (XVU_ELEMS * 2)         // 95,551,488
#define GUARD_BYTES 262144
#define WT_OFF_BYTES (XVU_BYTES + GUARD_BYTES)
#define WT_BYTES (COUT * KK * CIN * 2)    // 663,552
#define WS_NEEDED ((size_t)WT_OFF_BYTES + WT_BYTES)

__device__ __forceinline__ unsigned short f2bf(float f) {
  unsigned u = __float_as_uint(f);
  u += 0x7fffu + ((u >> 16) & 1u);        // round-to-nearest-even
  return (unsigned short)(u >> 16);
}

// ---------------------------------------------------------------------------
// convert_kernel: x[b][ci][iy][ix] fp32 -> xvu[b][uv][sy*48+sx][ci] bf16.
// iy = 9*sy + u, ix = 9*sx + v. One block per (b, u, sy): reads 64ci x 432px
// coalesced, transposes through LDS, writes 9 contiguous 6 KB chunks.
// ---------------------------------------------------------------------------
__global__ __launch_bounds__(256) void convert_kernel(
    const float* __restrict__ x, unsigned short* __restrict__ xvu) {
  __shared__ unsigned short lsm[ANG * HW * CIN];  // [v][sx][ci] = 27648
  int q  = blockIdx.x;
  int sy = q % HW;
  int u  = (q / HW) % ANG;
  int b  = q / (HW * ANG);
  int iy = sy * ANG + u;

  int t  = threadIdx.x;
  int ci = t >> 2;
  int qq = t & 3;
  const float* xr = x + ((size_t)(b * CIN + ci) * IN_HW + iy) * IN_HW + qq * 108;
  int v = 0, sx = qq * 12;
#pragma unroll
  for (int g = 0; g < 27; ++g) {
    float4 f = *(const float4*)(xr + g * 4);
    lsm[(v * HW + sx) * CIN + ci] = f2bf(f.x); v++; if (v == 9) { v = 0; sx++; }
    lsm[(v * HW + sx) * CIN + ci] = f2bf(f.y); v++; if (v == 9) { v = 0; sx++; }
    lsm[(v * HW + sx) * CIN + ci] = f2bf(f.z); v++; if (v == 9) { v = 0; sx++; }
    lsm[(v * HW + sx) * CIN + ci] = f2bf(f.w); v++; if (v == 9) { v = 0; sx++; }
  }
  __syncthreads();
  const uint4* ls4 = (const uint4*)lsm;             // 3456 uint4
  uint4* dst = (uint4*)xvu;
  for (int s = t; s < 3456; s += 256) {
    int v2 = s / 384;                               // 384 uint4 per v
    int r  = s - v2 * 384;
    size_t o4 = (size_t)(b * KK + u * ANG + v2) * (SPOS * CIN / 8)
              + (size_t)sy * (HW * CIN / 8) + r;
    dst[o4] = ls4[s];
  }
}

// ---------------------------------------------------------------------------
// wprep_kernel: wt[co][uv][ci] = bf16(w[co][ci][uv])
// ---------------------------------------------------------------------------
__global__ __launch_bounds__(256) void wprep_kernel(
    const float* __restrict__ w, unsigned short* __restrict__ wt) {
  int s = blockIdx.x * 256 + threadIdx.x;   // < 64*81*64 = 331776
  int ci = s & 63;
  int tt = s >> 6;
  int uv = tt % KK;
  int co = tt / KK;
  wt[s] = f2bf(w[((size_t)co * CIN + ci) * KK + uv]);
}

// ---------------------------------------------------------------------------
// conv_mfma_kernel: per (d,b): D[co][sp] = sum_{uv,ci} Wt[co][uv_src][ci] *
// xvu[b][uv][sp - d((u-4)*48+(v-4))][ci], MFMA 16x16x32 bf16, no LDS.
// Wave tile: M=64 co x N=48 spatial. Block = 4 waves = 192 spatial.
// Results stashed in d_out even-t slices 8*di (zeroed later by zero_kernel).
// ---------------------------------------------------------------------------
__global__ __launch_bounds__(256, 2) void conv_mfma_kernel(
    const unsigned short* __restrict__ xvu,
    const unsigned short* __restrict__ wt,
    float* __restrict__ out) {
  int q    = blockIdx.x;
  int mt12 = q % 12;
  int b    = (q / 12) & 3;
  int di   = q / 48;               // 0..8 -> d = di-4
  int d    = di - 4;

  int tid  = threadIdx.x;
  int wid  = tid >> 6;
  int lane = tid & 63;
  int n16  = lane & 15;
  int kq   = lane >> 4;
  int n0   = mt12 * 192 + wid * 48;

  const unsigned short* xb = xvu + (size_t)b * BSLAB;
  int zoff = (4 - b) * BSLAB;      // zeroed guard, elem offset from xb

  int msp[3], oyv[3], oxv[3], xoffn[3];
#pragma unroll
  for (int nt = 0; nt < 3; ++nt) {
    msp[nt]   = n0 + nt * 16 + n16;
    oyv[nt]   = msp[nt] / 48;
    oxv[nt]   = msp[nt] - oyv[nt] * 48;
    xoffn[nt] = msp[nt] * 64 + kq * 8;
  }
  int vw[4];
#pragma unroll
  for (int mt = 0; mt < 4; ++mt) {
    int co = mt * 16 + n16;
    vw[mt] = co * (KK * CIN) + kq * 8;
  }

  f32x4 acc[4][3];
#pragma unroll
  for (int mt = 0; mt < 4; ++mt)
#pragma unroll
    for (int nt = 0; nt < 3; ++nt) acc[mt][nt] = (f32x4){0.f, 0.f, 0.f, 0.f};

  short8 wf0[4][2], xf0[3][2], wf1[4][2], xf1[3][2];

  auto LOAD = [&](int uv, short8 (&wf)[4][2], short8 (&xf)[3][2]) {
    int u   = (uv * 57) >> 9;                 // uv/9 for uv<=80
    int v   = uv - u * 9;
    int uvs = (d > 0) ? (80 - uv) : uv;       // kernel flip for d>0
    const unsigned short* wp = wt + uvs * CIN;
#pragma unroll
    for (int mt = 0; mt < 4; ++mt) {
      wf[mt][0] = *(const short8*)(wp + vw[mt]);
      wf[mt][1] = *(const short8*)(wp + vw[mt] + 32);
    }
    int dy = d * (u - 4), dx = d * (v - 4);
    int soff = (uv * SPOS - (dy * 48 + dx)) * 64;
#pragma unroll
    for (int nt = 0; nt < 3; ++nt) {
      bool ok = ((unsigned)(oyv[nt] - dy) < 48u) && ((unsigned)(oxv[nt] - dx) < 48u);
      int off = ok ? (xoffn[nt] + soff) : zoff;
      xf[nt][0] = *(const short8*)(xb + off);
      xf[nt][1] = *(const short8*)(xb + off + 32);
    }
  };
  auto MF = [&](short8 (&wf)[4][2], short8 (&xf)[3][2]) {
#pragma unroll
    for (int mt = 0; mt < 4; ++mt)
#pragma unroll
      for (int nt = 0; nt < 3; ++nt) {
        acc[mt][nt] = __builtin_amdgcn_mfma_f32_16x16x32_bf16(
            wf[mt][0], xf[nt][0], acc[mt][nt], 0, 0, 0);
        acc[mt][nt] = __builtin_amdgcn_mfma_f32_16x16x32_bf16(
            wf[mt][1], xf[nt][1], acc[mt][nt], 0, 0, 0);
      }
  };

  LOAD(0, wf0, xf0);
#pragma unroll 1
  for (int uv = 0; uv < 80; uv += 2) {
    LOAD(uv + 1, wf1, xf1);
    MF(wf0, xf0);
    LOAD(uv + 2, wf0, xf0);   // max arg = 80
    MF(wf1, xf1);
  }
  MF(wf0, xf0);               // uv = 80

  // Epilogue: C/D layout col=lane&15 (spatial), row=kq*4+reg (co within tile)
#pragma unroll
  for (int mt = 0; mt < 4; ++mt) {
#pragma unroll
    for (int r = 0; r < 4; ++r) {
      int co = mt * 16 + kq * 4 + r;
      size_t ob = ((size_t)(b * COUT + co) * DDIM + 8 * di) * SPOS;
#pragma unroll
      for (int nt = 0; nt < 3; ++nt) out[ob + msp[nt]] = acc[mt][nt][r];
    }
  }
}

// ---------------------------------------------------------------------------
// blend / zero (unchanged from R1)
// ---------------------------------------------------------------------------
__global__ __launch_bounds__(256) void blend_kernel(float* __restrict__ out) {
  int p  = blockIdx.x * 256 + threadIdx.x;
  int bc = p / SPOS;
  int s  = p - bc * SPOS;
  size_t base = (size_t)bc * DDIM * SPOS + s;
  float tv[9];
#pragma unroll
  for (int j = 0; j < 9; ++j) tv[j] = out[base + (size_t)(8 * j) * SPOS];
#pragma unroll
  for (int j = 0; j < 8; ++j) {
    float v = 0.5f * (tv[j] + tv[j + 1]);
    size_t o = base + (size_t)(8 * j + 4) * SPOS;
    out[o] = v; out[o + SPOS] = v; out[o + 2 * SPOS] = v; out[o + 3 * SPOS] = v;
  }
}

__global__ __launch_bounds__(256) void zero_kernel(float* __restrict__ out) {
  int p  = blockIdx.x * 256 + threadIdx.x;
  int bc = p / SPOS;
  int s  = p - bc * SPOS;
  size_t base = (size_t)bc * DDIM * SPOS + s;
#pragma unroll
  for (int j = 0; j < 9; ++j) {
    size_t o = base + (size_t)(8 * j) * SPOS;
    out[o] = 0.f; out[o + SPOS] = 0.f; out[o + 2 * SPOS] = 0.f; out[o + 3 * SPOS] = 0.f;
  }
}

// ---------------------------------------------------------------------------
// R1 fallback conv (fp32, used only if ws_size is too small)
// ---------------------------------------------------------------------------
__global__ __launch_bounds__(256, 4) void conv_kernel(
    const float* __restrict__ x, const float* __restrict__ w,
    float* __restrict__ out) {
  __shared__ float lw[COUT * KK];
  __shared__ float lx[KK * 32];
  int bi  = blockIdx.x;
  int oxt = bi % 3;
  int oy2 = (bi / 3) % 24;
  int b   = (bi / 72) % BATCH;
  int di  = bi / 288;
  int d   = di - 4;
  int dil, pad;
  if (d < 0)       { dil = (-d) * ANG + 1; pad = (-d) * 36; }
  else if (d == 0) { dil = 1;              pad = 0; }
  else             { dil = d * ANG - 1;    pad = d * 36 - 8; }
  int t = threadIdx.x, tx = t & 15, ty = t >> 4;
  float acc[4][2] = {};
  const float* xb = x + (size_t)b * CIN * IN_HW * IN_HW;
  for (int ci = 0; ci < CIN; ++ci) {
    __syncthreads();
    for (int s = t; s < COUT * KK; s += 256) {
      int co = s / KK, k = s - co * KK;
      lw[s] = w[((size_t)co * CIN + ci) * KK + k];
    }
    const float* xc = xb + (size_t)ci * IN_HW * IN_HW;
    for (int s = t; s < KK * 32; s += 256) {
      int k = s >> 5, rem = s & 31, r = rem >> 4, c = rem & 15;
      int ky = k / ANG, kx = k - ky * ANG;
      int iy = (oy2 * 2 + r) * ANG - pad + ky * dil;
      int ix = (oxt * 16 + c) * ANG - pad + kx * dil;
      float vv = 0.f;
      if ((unsigned)iy < IN_HW && (unsigned)ix < IN_HW) vv = xc[iy * IN_HW + ix];
      lx[s] = vv;
    }
    __syncthreads();
    const float* lwp = lw + ty * 4 * KK;
#pragma unroll 9
    for (int k = 0; k < KK; ++k) {
      float x0 = lx[k * 32 + tx], x1 = lx[k * 32 + 16 + tx];
      float w0 = lwp[k], w1 = lwp[k + KK], w2 = lwp[k + 2 * KK], w3 = lwp[k + 3 * KK];
      acc[0][0] += w0 * x0; acc[0][1] += w0 * x1;
      acc[1][0] += w1 * x0; acc[1][1] += w1 * x1;
      acc[2][0] += w2 * x0; acc[2][1] += w2 * x1;
      acc[3][0] += w3 * x0; acc[3][1] += w3 * x1;
    }
  }
  int oy = oy2 * 2, ox = oxt * 16 + tx;
#pragma unroll
  for (int j = 0; j < 4; ++j) {
    int co = ty * 4 + j;
    size_t base = (((size_t)(b * COUT + co) * DDIM) + 8 * di) * SPOS;
    out[base + (size_t)oy * HW + ox]       = acc[j][0];
    out[base + (size_t)(oy + 1) * HW + ox] = acc[j][1];
  }
}

extern "C" void kernel_launch(void* const* d_in, const int* in_sizes, int n_in,
                              void* d_out, int out_size, void* d_ws, size_t ws_size,
                              hipStream_t stream) {
  const float* x = (const float*)d_in[0];   // [4, 64, 432, 432]
  const float* w = (const float*)d_in[1];   // [64, 64, 9, 9]
  float* out = (float*)d_out;               // [4, 64, 68, 48, 48]

  if (ws_size >= WS_NEEDED) {
    unsigned short* xvu = (unsigned short*)d_ws;
    unsigned short* wt  = (unsigned short*)((char*)d_ws + WT_OFF_BYTES);
    // zero the guard region (invalid sheared lanes read 0 from here)
    hipMemsetAsync((char*)d_ws + XVU_BYTES, 0, GUARD_BYTES, stream);
    wprep_kernel<<<dim3(1296), dim3(256), 0, stream>>>(w, wt);
    convert_kernel<<<dim3(BATCH * ANG * HW), dim3(256), 0, stream>>>(x, xvu);
    conv_mfma_kernel<<<dim3(9 * BATCH * 12), dim3(256), 0, stream>>>(xvu, wt, out);
  } else {
    conv_kernel<<<dim3(9 * 4 * 24 * 3), dim3(256), 0, stream>>>(x, w, out);
  }
  blend_kernel<<<dim3((BATCH * COUT * SPOS) / 256), dim3(256), 0, stream>>>(out);
  zero_kernel<<<dim3((BATCH * COUT * SPOS) / 256), dim3(256), 0, stream>>>(out);
}